// Round 7
// baseline (253.017 us; speedup 1.0000x reference)
//
#include <hip/hip_runtime.h>
#include <hip/hip_bf16.h>

// LinearFlexQMixer MI355X — round 15: packed bf16 conversion (header
// intrinsic, no asm). R14 post-mortem: p-split worked (qmix 156->141us);
// VALU is now the busiest pipe (VALUBusy 33% vs MFMA 11%) and ~1/3+ of it
// is manual 5-op RNE f32->bf16 in ctile_store (36 calls/wave) + Phase A
// (48 vals/wave). gfx950 does pairs in ONE op (v_cvt_pk_bf16_f32).
// Single change vs R14: f2bf pairs -> __float22bfloat162_rn (RNE, same
// rounding -> absmax must stay 0.0029). No reordering, no inline asm
// (isolates R12's NaN: pass => aw2-deferral was the bug).
// prep_kernel + all scheduling byte-identical to R14.

#define NA 16
#define NEn 128
#define EDm 96
#define ST 136  // LDS row stride (shorts); 272B rows -> <=2-way conflicts

typedef __attribute__((ext_vector_type(8))) short bf16x8;
typedef __attribute__((ext_vector_type(4))) float f32x4;

#define MFMA(a, b, c) __builtin_amdgcn_mfma_f32_16x16x32_bf16((a), (b), (c), 0, 0, 0)
#define LGKM0() __asm__ volatile("s_waitcnt lgkmcnt(0)" ::: "memory")

// d_ws layout (bf16 elems), per hypernet p at p*HYPE:
#define OFF_W1 0       // [nt8][kt3][64][8]  B-frags Phase A (fc1w)
#define OFF_WQ 12288   // [nt8][kt4][64][8]  B-frags Q (inw cols 0:128, pre-scaled)
#define OFF_WK 28672   // [h4][nt8][64][8]   B-frags qW (Wk^T per head, K=32)
#define OFF_WV 45056   // [h4][mt2][kt4][64][8] A-frags V^T (Wv^T per head)
#define OFF_WO 61440   // [nt8][kt4][64][8]  B-frags OUT (outw)
#define OFF_W2 77824   // [nt2][kt4][64][8]  B-frags X3 (fc2w)
#define HYPE 81920
#define WS_FLAG_OFF 327680  // int flag: mask dtype (1 => int32)

__device__ __forceinline__ unsigned short f2bf(float f) {
  unsigned u = __float_as_uint(f);
  u += 0x7fffu + ((u >> 16) & 1u);  // RNE
  return (unsigned short)(u >> 16);
}

// Pack two f32 -> dword of 2 bf16 (RNE) via HW v_cvt_pk_bf16_f32.
// Header intrinsic (not asm): compiler sees full dataflow.
__device__ __forceinline__ unsigned cvt_pk2(float lo, float hi) {
  union { __hip_bfloat162 h2; unsigned u; } cv;
  cv.h2 = __float22bfloat162_rn(float2{lo, hi});
  return cv.u;  // low half = lo, high half = hi (matches manual pack)
}

// Store one 16x16 C-tile column (4 f32, rows row0+0..3, col) as bf16 into
// LDS row-major [..][ST]. Pairs lanes (col, col^1) via shfl so every dword
// is written by exactly one lane. Full-wave calls only.
__device__ __forceinline__ void ctile_store(unsigned short* dst, int row0,
                                            int col, f32x4 v) {
  unsigned x = cvt_pk2(v[0], v[1]);
  unsigned y = cvt_pk2(v[2], v[3]);
  unsigned ox = (unsigned)__shfl_xor((int)x, 1);
  unsigned oy = (unsigned)__shfl_xor((int)y, 1);
  unsigned w0, w1;
  int ra;
  if ((threadIdx.x & 1) == 0) {
    ra = 0;
    w0 = (x & 0xffffu) | (ox << 16);
    w1 = (x >> 16) | (ox & 0xffff0000u);
  } else {
    ra = 2;
    w0 = (oy & 0xffffu) | (y << 16);
    w1 = (oy >> 16) | (y & 0xffff0000u);
  }
  *(unsigned*)(dst + (row0 + ra) * ST + (col & ~1)) = w0;
  *(unsigned*)(dst + (row0 + ra + 1) * ST + (col & ~1)) = w1;
}

// ---- prep (R11): destination-ordered gather. 80 work blocks + 1 mask blk.
__global__ void prep_kernel(const float* __restrict__ w_fc1w,
                            const float* __restrict__ w_inw,
                            const float* __restrict__ w_outw,
                            const float* __restrict__ w_fc2w,
                            const float* __restrict__ v_fc1w,
                            const float* __restrict__ v_inw,
                            const float* __restrict__ v_outw,
                            const float* __restrict__ v_fc2w,
                            const unsigned char* __restrict__ mask,
                            unsigned short* __restrict__ ws,
                            int* __restrict__ flag) {
  if (blockIdx.x == 80) {
    const uint4 v = *(const uint4*)(mask + threadIdx.x * 16);
    const unsigned nz = (v.x | v.y | v.z | v.w) & 0xffffff00u;
    const int any = __syncthreads_or((int)(nz != 0));
    if (threadIdx.x == 0) *flag = (any == 0) ? 1 : 0;
    return;
  }
  const int g = blockIdx.x * 256 + threadIdx.x;  // 0 .. 20479
  const int p = (g >= 10240) ? 1 : 0;
  const int i = g - p * 10240;
  const int l = i & 63;
  const int tt = i >> 6;  // 0..159
  const int lhi = l >> 4, lo = l & 15;
  const float* fc1w = p ? v_fc1w : w_fc1w;
  const float* inw = p ? v_inw : w_inw;
  const float* outw = p ? v_outw : w_outw;
  const float* fc2w = p ? v_fc2w : w_fc2w;
  unsigned short* wsp = ws + p * HYPE;

  float v8[8];
  unsigned short* dst;
  if (tt < 24) {
    const int nt = tt / 3, kt = tt - nt * 3;
    const float* src = fc1w + (kt * 32 + lhi * 8) * 128 + nt * 16 + lo;
#pragma unroll
    for (int j = 0; j < 8; ++j) v8[j] = src[j * 128];
    dst = wsp + OFF_W1 + tt * 512 + l * 8;
  } else if (tt < 56) {
    const int t2 = tt - 24;
    const int nt = t2 >> 2, kt = t2 & 3;
    const float* src = inw + (kt * 32 + lhi * 8) * 384 + nt * 16 + lo;
#pragma unroll
    for (int j = 0; j < 8; ++j) v8[j] = src[j * 384] * 0.17677669529663687f;
    dst = wsp + OFF_WQ + t2 * 512 + l * 8;
  } else if (tt < 88) {
    const int t2 = tt - 56;
    const int h = t2 >> 3, nt = t2 & 7;
    const float* src = inw + (nt * 16 + lo) * 384 + 128 + h * 32 + lhi * 8;
#pragma unroll
    for (int j = 0; j < 8; ++j) v8[j] = src[j];
    dst = wsp + OFF_WK + t2 * 512 + l * 8;
  } else if (tt < 120) {
    const int t2 = tt - 88;
    const int kt = t2 & 3, q = t2 >> 2;
    const int h = q >> 1, mt = q & 1;
    const float* src =
        inw + (kt * 32 + lhi * 8) * 384 + 256 + h * 32 + mt * 16 + lo;
#pragma unroll
    for (int j = 0; j < 8; ++j) v8[j] = src[j * 384];
    dst = wsp + OFF_WV + t2 * 512 + l * 8;
  } else if (tt < 152) {
    const int t2 = tt - 120;
    const int nt = t2 >> 2, kt = t2 & 3;
    const float* src = outw + (kt * 32 + lhi * 8) * 128 + nt * 16 + lo;
#pragma unroll
    for (int j = 0; j < 8; ++j) v8[j] = src[j * 128];
    dst = wsp + OFF_WO + t2 * 512 + l * 8;
  } else {
    const int t2 = tt - 152;
    const int nt = t2 >> 2, kt = t2 & 3;
    const float* src = fc2w + (kt * 32 + lhi * 8) * 32 + nt * 16 + lo;
#pragma unroll
    for (int j = 0; j < 8; ++j) v8[j] = src[j * 32];
    dst = wsp + OFF_W2 + t2 * 512 + l * 8;
  }
  bf16x8 o;
#pragma unroll
  for (int j = 0; j < 8; ++j) o[j] = (short)f2bf(v8[j]);
  *(bf16x8*)dst = o;
}

// LDS (bytes) — overlay map (unchanged from R10..R14):
//   sx1 / vtbuf [128][136]bf16   0..34816
//   sSlice 4x[16][136]           34816..52224  (per-wave transpose slices)
//     sattn ALIASES sSlice+0     (live post-B2 only; slices dead)
//     sout  ALIASES sSlice+4352  (live post-B3 only)
//   sres f32[32]                 52224..52352  (only [0..15] used)
//   sm   u8[128]                 52352..52480
// 52,480 B/block -> 3 blocks/CU resource limit (160KB/CU).
#define SMEM_BYTES 52480

__global__ __launch_bounds__(256, 2) void qmix_mfma(
    const float* __restrict__ agent_qs, const float* __restrict__ entities,
    const unsigned char* __restrict__ emask_g,
    const unsigned short* __restrict__ wsw, const int* __restrict__ mflag,
    const float* __restrict__ w_fc1b, const float* __restrict__ w_outb,
    const float* __restrict__ w_fc2b, const float* __restrict__ v_fc1b,
    const float* __restrict__ v_outb, const float* __restrict__ v_fc2b,
    float* __restrict__ out_g) {
  const int t = threadIdx.x;
  const int wv = t >> 6;  // wave == head
  const int ln = t & 63;
  const int lr = ln & 15;
  const int lq = ln >> 4;
  const int b = blockIdx.x >> 1;   // batch element
  const int p = blockIdx.x & 1;    // hypernet (0: w1, 1: v)
  const float* ents = entities + (size_t)b * (NEn * EDm);

  __shared__ __align__(16) unsigned char smem[SMEM_BYTES];
  unsigned short* sx1 = (unsigned short*)smem;  // also vtbuf
  unsigned short* sSlice = sx1 + 17408;         // 4 slices
  unsigned short* sattn = sSlice;               // alias: live post-B2 only
  unsigned short* sout = sSlice + 16 * ST;      // alias: live post-B3 only
  float* sres = (float*)(smem + 52224);
  unsigned char* sm = smem + 52352;
  unsigned short* sS = sSlice + wv * 16 * ST;  // this wave's slice

  // ---- entity mask (dtype-normalized) ----
  const int is_i32 = *mflag;
  int mv = 1;
  if (t < NEn) {
    if (is_i32)
      mv = (((const int*)emask_g)[(size_t)b * NEn + t] != 0) ? 1 : 0;
    else
      mv = (emask_g[(size_t)b * NEn + t] != 0) ? 1 : 0;
    sm[t] = (unsigned char)mv;
  }
  const int allE = __syncthreads_and(mv);

  const unsigned short* wsb = wsw + (size_t)p * HYPE;
  const float* fc1b = p ? v_fc1b : w_fc1b;
  const float* outb = p ? v_outb : w_outb;
  const float* fc2b = p ? v_fc2b : w_fc2b;

  // ---- Phase A (co-op): x1 = relu(E @ W1 + b) -> sx1 [e][m] ----
  {
#pragma unroll
    for (int mi = 0; mi < 2; ++mi) {
      const int mt = wv * 2 + mi;
      bf16x8 af[3];
      const float* erow = ents + (mt * 16 + lr) * EDm + lq * 8;
#pragma unroll
      for (int kt = 0; kt < 3; ++kt) {
        float4 u = *(const float4*)(erow + kt * 32);
        float4 w = *(const float4*)(erow + kt * 32 + 4);
        union { unsigned u32[4]; bf16x8 v8; } cv;
        cv.u32[0] = cvt_pk2(u.x, u.y);
        cv.u32[1] = cvt_pk2(u.z, u.w);
        cv.u32[2] = cvt_pk2(w.x, w.y);
        cv.u32[3] = cvt_pk2(w.z, w.w);
        af[kt] = cv.v8;
      }
#pragma unroll
      for (int nt = 0; nt < 8; ++nt) {
        f32x4 acc = {0.f, 0.f, 0.f, 0.f};
        const unsigned short* bp = wsb + OFF_W1 + (nt * 3) * 512 + ln * 8;
#pragma unroll
        for (int kt = 0; kt < 3; ++kt)
          acc = MFMA(af[kt], *(const bf16x8*)(bp + kt * 512), acc);
        const float bias = fc1b[nt * 16 + lr];
        f32x4 r;
        r[0] = fmaxf(acc[0] + bias, 0.f); r[1] = fmaxf(acc[1] + bias, 0.f);
        r[2] = fmaxf(acc[2] + bias, 0.f); r[3] = fmaxf(acc[3] + bias, 0.f);
        ctile_store(sx1, mt * 16 + lq * 4, nt * 16 + lr, r);
      }
    }
  }
  __syncthreads();  // B1: x1 complete

  // ---- Q (own head): Q_h[q][d] -> transpose via slice -> aQ ----
  {
    bf16x8 aq[4];
#pragma unroll
    for (int kt = 0; kt < 4; ++kt)
      aq[kt] = *(const bf16x8*)(sx1 + lr * ST + kt * 32 + lq * 8);
#pragma unroll
    for (int ni = 0; ni < 2; ++ni) {
      const int nt = wv * 2 + ni;
      f32x4 acc = {0.f, 0.f, 0.f, 0.f};
      const unsigned short* bp = wsb + OFF_WQ + (nt * 4) * 512 + ln * 8;
#pragma unroll
      for (int kt = 0; kt < 4; ++kt)
        acc = MFMA(aq[kt], *(const bf16x8*)(bp + kt * 512), acc);
      ctile_store(sS, lq * 4, ni * 16 + lr, acc);  // local d cols 0..31
    }
  }
  // hoist qW's global WK B-frags above the transpose drain (independent)
  bf16x8 wk[8];
#pragma unroll
  for (int nt = 0; nt < 8; ++nt)
    wk[nt] = *(const bf16x8*)(wsb + OFF_WK + (wv * 8 + nt) * 512 + ln * 8);
  LGKM0();
  const bf16x8 aQ = *(const bf16x8*)(sS + lr * ST + lq * 8);  // A[q][d0..31]

  // ---- qW = Q_h @ Wk_h^T (8 m-tiles) -> transpose -> aw ----
  {
    f32x4 Cw[8];
#pragma unroll
    for (int nt = 0; nt < 8; ++nt) {
      f32x4 acc = {0.f, 0.f, 0.f, 0.f};
      Cw[nt] = MFMA(aQ, wk[nt], acc);
    }
#pragma unroll
    for (int nt = 0; nt < 8; ++nt)
      ctile_store(sS, lq * 4, nt * 16 + lr, Cw[nt]);
  }
  LGKM0();
  bf16x8 aw[4];
#pragma unroll
  for (int kt = 0; kt < 4; ++kt)
    aw[kt] = *(const bf16x8*)(sS + lr * ST + kt * 32 + lq * 8);

  // ---- logits (full width, in-wave): Cl[nt] = qW @ x1^T ----
  f32x4 Cl[8];
  __builtin_amdgcn_s_setprio(1);
#pragma unroll
  for (int nt = 0; nt < 8; ++nt) {
    f32x4 acc = {0.f, 0.f, 0.f, 0.f};
#pragma unroll
    for (int kt = 0; kt < 4; ++kt) {
      const bf16x8 bx =
          *(const bf16x8*)(sx1 + (nt * 16 + lr) * ST + kt * 32 + lq * 8);
      acc = MFMA(aw[kt], bx, acc);
    }
    Cl[nt] = acc;
  }
  __builtin_amdgcn_s_setprio(0);

  // ---- in-wave softmax over 128 cols ----
  {
    float lv[8][4];
#pragma unroll
    for (int nt = 0; nt < 8; ++nt) {
      const int eM = sm[nt * 16 + lr];
#pragma unroll
      for (int r = 0; r < 4; ++r) lv[nt][r] = eM ? -1e9f : Cl[nt][r];
    }
    float mx[4], sl[4];
#pragma unroll
    for (int r = 0; r < 4; ++r) {
      float m = lv[0][r];
#pragma unroll
      for (int nt = 1; nt < 8; ++nt) m = fmaxf(m, lv[nt][r]);
      mx[r] = m;
    }
#pragma unroll
    for (int k = 1; k < 16; k <<= 1)
#pragma unroll
      for (int r = 0; r < 4; ++r) mx[r] = fmaxf(mx[r], __shfl_xor(mx[r], k));
    float ex[8][4];
#pragma unroll
    for (int r = 0; r < 4; ++r) sl[r] = 0.f;
#pragma unroll
    for (int nt = 0; nt < 8; ++nt)
#pragma unroll
      for (int r = 0; r < 4; ++r) {
        ex[nt][r] = __expf(lv[nt][r] - mx[r]);
        sl[r] += ex[nt][r];
      }
#pragma unroll
    for (int k = 1; k < 16; k <<= 1)
#pragma unroll
      for (int r = 0; r < 4; ++r) sl[r] += __shfl_xor(sl[r], k);
    float sc[4];
#pragma unroll
    for (int r = 0; r < 4; ++r)
      sc[r] = ((int)sm[lq * 4 + r] | allE) ? 0.f : (1.f / sl[r]);
#pragma unroll
    for (int nt = 0; nt < 8; ++nt) {
      f32x4 wv4;
#pragma unroll
      for (int r = 0; r < 4; ++r) wv4[r] = ex[nt][r] * sc[r];
      ctile_store(sS, lq * 4, nt * 16 + lr, wv4);  // W, overwrites qW
    }
  }
  LGKM0();
  bf16x8 aw2[4];
#pragma unroll
  for (int kt = 0; kt < 4; ++kt)
    aw2[kt] = *(const bf16x8*)(sS + lr * ST + kt * 32 + lq * 8);
  // sS (all slices) dead from here on.

  // ---- V^T_h = Wv_h^T @ x1^T into regs (x1 still live) ----
  f32x4 Cv[2][8];
  __builtin_amdgcn_s_setprio(1);
#pragma unroll
  for (int mt = 0; mt < 2; ++mt) {
    bf16x8 av[4];
#pragma unroll
    for (int kt = 0; kt < 4; ++kt)
      av[kt] = *(const bf16x8*)(wsb + OFF_WV +
                                (((wv * 2 + mt) * 4) + kt) * 512 + ln * 8);
#pragma unroll
    for (int nt = 0; nt < 8; ++nt) {
      f32x4 acc = {0.f, 0.f, 0.f, 0.f};
#pragma unroll
      for (int kt = 0; kt < 4; ++kt) {
        const bf16x8 bx =
            *(const bf16x8*)(sx1 + (nt * 16 + lr) * ST + kt * 32 + lq * 8);
        acc = MFMA(av[kt], bx, acc);
      }
      Cv[mt][nt] = acc;
    }
  }
  __builtin_amdgcn_s_setprio(0);
  __syncthreads();  // B2: x1 dead -> vtbuf; slices dead -> sattn valid

  // ---- write V^T into own 32-row band of vtbuf; attn = W @ V_h ----
  {
#pragma unroll
    for (int mt = 0; mt < 2; ++mt)
#pragma unroll
      for (int nt = 0; nt < 8; ++nt)
        ctile_store(sx1, wv * 32 + mt * 16 + lq * 4, nt * 16 + lr,
                    Cv[mt][nt]);
  }
  LGKM0();
  {
#pragma unroll
    for (int ntd = 0; ntd < 2; ++ntd) {
      f32x4 acc = {0.f, 0.f, 0.f, 0.f};
#pragma unroll
      for (int kt = 0; kt < 4; ++kt) {
        const bf16x8 bv = *(const bf16x8*)(sx1 + (wv * 32 + ntd * 16 + lr) *
                                                     ST +
                                           kt * 32 + lq * 8);
        acc = MFMA(aw2[kt], bv, acc);
      }
      ctile_store(sattn, lq * 4, wv * 32 + ntd * 16 + lr, acc);
    }
  }
  // hoist OUT's WO B-frags across B3 (independent of sattn)
  bf16x8 wo[2][4];
#pragma unroll
  for (int ni = 0; ni < 2; ++ni) {
    const unsigned short* bp =
        wsb + OFF_WO + ((wv * 2 + ni) * 4) * 512 + ln * 8;
#pragma unroll
    for (int kt = 0; kt < 4; ++kt)
      wo[ni][kt] = *(const bf16x8*)(bp + kt * 512);
  }
  __syncthreads();  // B3: sattn complete; sout region (slice 1) writable

  // ---- OUT = attn @ Wo + bo -> sout (co-op, 2 n-tiles/wave) ----
  {
    bf16x8 aa[4];
#pragma unroll
    for (int kt = 0; kt < 4; ++kt)
      aa[kt] = *(const bf16x8*)(sattn + lr * ST + kt * 32 + lq * 8);
#pragma unroll
    for (int ni = 0; ni < 2; ++ni) {
      const int nt = wv * 2 + ni;
      f32x4 acc = {0.f, 0.f, 0.f, 0.f};
#pragma unroll
      for (int kt = 0; kt < 4; ++kt)
        acc = MFMA(aa[kt], wo[ni][kt], acc);
      const float bj = outb[nt * 16 + lr];
      f32x4 r;
      r[0] = acc[0] + bj; r[1] = acc[1] + bj;
      r[2] = acc[2] + bj; r[3] = acc[3] + bj;
      ctile_store(sout, lq * 4, nt * 16 + lr, r);
    }
  }
  // hoist X3's W2 B-frags across B4 (independent of sout)
  bf16x8 w2f[2][4];
#pragma unroll
  for (int nt = 0; nt < 2; ++nt) {
    const unsigned short* bp = wsb + OFF_W2 + (nt * 4) * 512 + ln * 8;
#pragma unroll
    for (int kt = 0; kt < 4; ++kt)
      w2f[nt][kt] = *(const bf16x8*)(bp + kt * 512);
  }
  __syncthreads();  // B4: sout complete

  // ---- X3 = out @ fc2 + b (redundant per wave), mask, row-sum ----
  {
    bf16x8 ao[4];
#pragma unroll
    for (int kt = 0; kt < 4; ++kt)
      ao[kt] = *(const bf16x8*)(sout + lr * ST + kt * 32 + lq * 8);
    f32x4 Cx[2];
#pragma unroll
    for (int nt = 0; nt < 2; ++nt) {
      f32x4 acc = {0.f, 0.f, 0.f, 0.f};
#pragma unroll
      for (int kt = 0; kt < 4; ++kt)
        acc = MFMA(ao[kt], w2f[nt][kt], acc);
      Cx[nt] = acc;
    }
    const float b0 = fc2b[lr], b1 = fc2b[16 + lr];
    float rs[4];
#pragma unroll
    for (int r = 0; r < 4; ++r) {
      const int row = lq * 4 + r;
      rs[r] = sm[row] ? 0.f : (Cx[0][r] + b0 + Cx[1][r] + b1);
    }
#pragma unroll
    for (int k = 1; k < 16; k <<= 1)
#pragma unroll
      for (int r = 0; r < 4; ++r) rs[r] += __shfl_xor(rs[r], k);
    if (wv == 0 && lr == 0) {
#pragma unroll
      for (int r = 0; r < 4; ++r) {
        const int q = lq * 4 + r;
        sres[q] = p ? rs[r] : fabsf(rs[r]) * (1.f / 32.f);
      }
    }
  }

  __syncthreads();
  if (t == 0) {
    float s = 0.f;
    if (p == 0) {
      const float* qs = agent_qs + (size_t)b * NA;
#pragma unroll
      for (int q = 0; q < NA; ++q) s += qs[q] * sres[q];
    } else {
#pragma unroll
      for (int q = 0; q < NA; ++q) s += sres[q];
      s *= (1.f / 512.f);
    }
    atomicAdd(out_g + b, s);  // out zeroed by harness memset; 2 addends/b
  }
}

extern "C" void kernel_launch(void* const* d_in, const int* in_sizes, int n_in,
                              void* d_out, int out_size, void* d_ws,
                              size_t ws_size, hipStream_t stream) {
  (void)n_in; (void)out_size; (void)ws_size;
  const int nb = in_sizes[0] / NA;  // BS*T = 1600
  unsigned short* wsw = (unsigned short*)d_ws;
  int* mflag = (int*)((char*)d_ws + WS_FLAG_OFF);

  hipLaunchKernelGGL(prep_kernel, dim3(81), dim3(256), 0, stream,
                     (const float*)d_in[3], (const float*)d_in[5],
                     (const float*)d_in[6], (const float*)d_in[8],
                     (const float*)d_in[10], (const float*)d_in[12],
                     (const float*)d_in[13], (const float*)d_in[15],
                     (const unsigned char*)d_in[2], wsw, mflag);
  hipLaunchKernelGGL(qmix_mfma, dim3(nb * 2), dim3(256), 0, stream,
                     (const float*)d_in[0], (const float*)d_in[1],
                     (const unsigned char*)d_in[2], (const unsigned short*)wsw,
                     (const int*)mflag, (const float*)d_in[4],
                     (const float*)d_in[7], (const float*)d_in[9],
                     (const float*)d_in[11], (const float*)d_in[14],
                     (const float*)d_in[16], (float*)d_out);
}

// Round 8
// 243.735 us; speedup vs baseline: 1.0381x; 1.0381x over previous
//
#include <hip/hip_runtime.h>
#include <hip/hip_bf16.h>

// LinearFlexQMixer MI355X — round 16: latency-overlap bundle (no new
// memory-order semantics). R15 post-mortem: cvt_pk neutral -> VALU not
// critical; chain is latency-bound (~34K cy wall/block for ~15-20K issue).
// Changes vs R15 (all issue-order only, LDS op order per region unchanged):
//  (1) E-prefetch: Phase A's 12 float4 HBM loads issued at kernel top,
//      before mask+barrier (hides ~900cy cold-HBM under mask phase).
//  (2) Softmax off critical path: logits -> V^T(mt=0) -> softmax+W-store ->
//      V^T(mt=1) -> lgkmcnt -> aw2. mt=0 MFMAs drain under softmax VALU;
//      W-store->aw2 round trip hides under mt=1's 32 MFMAs.
//  (3) Final __syncthreads -> lgkmcnt(0) (sres is wave-0-private).
// VGPR guard: peaks ~116 at V^T(mt=1); must stay <=128 (cliff at 128).
// prep_kernel identical to R11.

#define NA 16
#define NEn 128
#define EDm 96
#define ST 136  // LDS row stride (shorts); 272B rows -> <=2-way conflicts

typedef __attribute__((ext_vector_type(8))) short bf16x8;
typedef __attribute__((ext_vector_type(4))) float f32x4;

#define MFMA(a, b, c) __builtin_amdgcn_mfma_f32_16x16x32_bf16((a), (b), (c), 0, 0, 0)
#define LGKM0() __asm__ volatile("s_waitcnt lgkmcnt(0)" ::: "memory")

// d_ws layout (bf16 elems), per hypernet p at p*HYPE:
#define OFF_W1 0       // [nt8][kt3][64][8]  B-frags Phase A (fc1w)
#define OFF_WQ 12288   // [nt8][kt4][64][8]  B-frags Q (inw cols 0:128, pre-scaled)
#define OFF_WK 28672   // [h4][nt8][64][8]   B-frags qW (Wk^T per head, K=32)
#define OFF_WV 45056   // [h4][mt2][kt4][64][8] A-frags V^T (Wv^T per head)
#define OFF_WO 61440   // [nt8][kt4][64][8]  B-frags OUT (outw)
#define OFF_W2 77824   // [nt2][kt4][64][8]  B-frags X3 (fc2w)
#define HYPE 81920
#define WS_FLAG_OFF 327680  // int flag: mask dtype (1 => int32)

__device__ __forceinline__ unsigned short f2bf(float f) {
  unsigned u = __float_as_uint(f);
  u += 0x7fffu + ((u >> 16) & 1u);  // RNE
  return (unsigned short)(u >> 16);
}

// Pack two f32 -> dword of 2 bf16 (RNE) via HW v_cvt_pk_bf16_f32.
__device__ __forceinline__ unsigned cvt_pk2(float lo, float hi) {
  union { __hip_bfloat162 h2; unsigned u; } cv;
  cv.h2 = __float22bfloat162_rn(float2{lo, hi});
  return cv.u;
}

// Store one 16x16 C-tile column (4 f32, rows row0+0..3, col) as bf16 into
// LDS row-major [..][ST]. Pairs lanes (col, col^1) via shfl so every dword
// is written by exactly one lane. Full-wave calls only.
__device__ __forceinline__ void ctile_store(unsigned short* dst, int row0,
                                            int col, f32x4 v) {
  unsigned x = cvt_pk2(v[0], v[1]);
  unsigned y = cvt_pk2(v[2], v[3]);
  unsigned ox = (unsigned)__shfl_xor((int)x, 1);
  unsigned oy = (unsigned)__shfl_xor((int)y, 1);
  unsigned w0, w1;
  int ra;
  if ((threadIdx.x & 1) == 0) {
    ra = 0;
    w0 = (x & 0xffffu) | (ox << 16);
    w1 = (x >> 16) | (ox & 0xffff0000u);
  } else {
    ra = 2;
    w0 = (oy & 0xffffu) | (y << 16);
    w1 = (oy >> 16) | (y & 0xffff0000u);
  }
  *(unsigned*)(dst + (row0 + ra) * ST + (col & ~1)) = w0;
  *(unsigned*)(dst + (row0 + ra + 1) * ST + (col & ~1)) = w1;
}

// ---- prep (R11): destination-ordered gather. 80 work blocks + 1 mask blk.
__global__ void prep_kernel(const float* __restrict__ w_fc1w,
                            const float* __restrict__ w_inw,
                            const float* __restrict__ w_outw,
                            const float* __restrict__ w_fc2w,
                            const float* __restrict__ v_fc1w,
                            const float* __restrict__ v_inw,
                            const float* __restrict__ v_outw,
                            const float* __restrict__ v_fc2w,
                            const unsigned char* __restrict__ mask,
                            unsigned short* __restrict__ ws,
                            int* __restrict__ flag) {
  if (blockIdx.x == 80) {
    const uint4 v = *(const uint4*)(mask + threadIdx.x * 16);
    const unsigned nz = (v.x | v.y | v.z | v.w) & 0xffffff00u;
    const int any = __syncthreads_or((int)(nz != 0));
    if (threadIdx.x == 0) *flag = (any == 0) ? 1 : 0;
    return;
  }
  const int g = blockIdx.x * 256 + threadIdx.x;  // 0 .. 20479
  const int p = (g >= 10240) ? 1 : 0;
  const int i = g - p * 10240;
  const int l = i & 63;
  const int tt = i >> 6;  // 0..159
  const int lhi = l >> 4, lo = l & 15;
  const float* fc1w = p ? v_fc1w : w_fc1w;
  const float* inw = p ? v_inw : w_inw;
  const float* outw = p ? v_outw : w_outw;
  const float* fc2w = p ? v_fc2w : w_fc2w;
  unsigned short* wsp = ws + p * HYPE;

  float v8[8];
  unsigned short* dst;
  if (tt < 24) {
    const int nt = tt / 3, kt = tt - nt * 3;
    const float* src = fc1w + (kt * 32 + lhi * 8) * 128 + nt * 16 + lo;
#pragma unroll
    for (int j = 0; j < 8; ++j) v8[j] = src[j * 128];
    dst = wsp + OFF_W1 + tt * 512 + l * 8;
  } else if (tt < 56) {
    const int t2 = tt - 24;
    const int nt = t2 >> 2, kt = t2 & 3;
    const float* src = inw + (kt * 32 + lhi * 8) * 384 + nt * 16 + lo;
#pragma unroll
    for (int j = 0; j < 8; ++j) v8[j] = src[j * 384] * 0.17677669529663687f;
    dst = wsp + OFF_WQ + t2 * 512 + l * 8;
  } else if (tt < 88) {
    const int t2 = tt - 56;
    const int h = t2 >> 3, nt = t2 & 7;
    const float* src = inw + (nt * 16 + lo) * 384 + 128 + h * 32 + lhi * 8;
#pragma unroll
    for (int j = 0; j < 8; ++j) v8[j] = src[j];
    dst = wsp + OFF_WK + t2 * 512 + l * 8;
  } else if (tt < 120) {
    const int t2 = tt - 88;
    const int kt = t2 & 3, q = t2 >> 2;
    const int h = q >> 1, mt = q & 1;
    const float* src =
        inw + (kt * 32 + lhi * 8) * 384 + 256 + h * 32 + mt * 16 + lo;
#pragma unroll
    for (int j = 0; j < 8; ++j) v8[j] = src[j * 384];
    dst = wsp + OFF_WV + t2 * 512 + l * 8;
  } else if (tt < 152) {
    const int t2 = tt - 120;
    const int nt = t2 >> 2, kt = t2 & 3;
    const float* src = outw + (kt * 32 + lhi * 8) * 128 + nt * 16 + lo;
#pragma unroll
    for (int j = 0; j < 8; ++j) v8[j] = src[j * 128];
    dst = wsp + OFF_WO + t2 * 512 + l * 8;
  } else {
    const int t2 = tt - 152;
    const int nt = t2 >> 2, kt = t2 & 3;
    const float* src = fc2w + (kt * 32 + lhi * 8) * 32 + nt * 16 + lo;
#pragma unroll
    for (int j = 0; j < 8; ++j) v8[j] = src[j * 32];
    dst = wsp + OFF_W2 + t2 * 512 + l * 8;
  }
  bf16x8 o;
#pragma unroll
  for (int j = 0; j < 8; ++j) o[j] = (short)f2bf(v8[j]);
  *(bf16x8*)dst = o;
}

// LDS (bytes) — overlay map (unchanged from R10..R15):
//   sx1 / vtbuf [128][136]bf16   0..34816
//   sSlice 4x[16][136]           34816..52224  (per-wave transpose slices)
//     sattn ALIASES sSlice+0     (live post-B2 only; slices dead)
//     sout  ALIASES sSlice+4352  (live post-B3 only)
//   sres f32[32]                 52224..52352  (only [0..15] used)
//   sm   u8[128]                 52352..52480
// 52,480 B/block -> 3 blocks/CU resource limit (160KB/CU).
#define SMEM_BYTES 52480

__global__ __launch_bounds__(256, 2) void qmix_mfma(
    const float* __restrict__ agent_qs, const float* __restrict__ entities,
    const unsigned char* __restrict__ emask_g,
    const unsigned short* __restrict__ wsw, const int* __restrict__ mflag,
    const float* __restrict__ w_fc1b, const float* __restrict__ w_outb,
    const float* __restrict__ w_fc2b, const float* __restrict__ v_fc1b,
    const float* __restrict__ v_outb, const float* __restrict__ v_fc2b,
    float* __restrict__ out_g) {
  const int t = threadIdx.x;
  const int wv = t >> 6;  // wave == head
  const int ln = t & 63;
  const int lr = ln & 15;
  const int lq = ln >> 4;
  const int b = blockIdx.x >> 1;   // batch element
  const int p = blockIdx.x & 1;    // hypernet (0: w1, 1: v)
  const float* ents = entities + (size_t)b * (NEn * EDm);

  __shared__ __align__(16) unsigned char smem[SMEM_BYTES];
  unsigned short* sx1 = (unsigned short*)smem;  // also vtbuf
  unsigned short* sSlice = sx1 + 17408;         // 4 slices
  unsigned short* sattn = sSlice;               // alias: live post-B2 only
  unsigned short* sout = sSlice + 16 * ST;      // alias: live post-B3 only
  float* sres = (float*)(smem + 52224);
  unsigned char* sm = smem + 52352;
  unsigned short* sS = sSlice + wv * 16 * ST;  // this wave's slice

  // ---- E-prefetch: issue Phase A's HBM loads before anything else ----
  float4 eu[2][3], ev[2][3];
#pragma unroll
  for (int mi = 0; mi < 2; ++mi) {
    const float* erow = ents + ((wv * 2 + mi) * 16 + lr) * EDm + lq * 8;
#pragma unroll
    for (int kt = 0; kt < 3; ++kt) {
      eu[mi][kt] = *(const float4*)(erow + kt * 32);
      ev[mi][kt] = *(const float4*)(erow + kt * 32 + 4);
    }
  }

  // ---- entity mask (dtype-normalized) ----
  const int is_i32 = *mflag;
  int mv = 1;
  if (t < NEn) {
    if (is_i32)
      mv = (((const int*)emask_g)[(size_t)b * NEn + t] != 0) ? 1 : 0;
    else
      mv = (emask_g[(size_t)b * NEn + t] != 0) ? 1 : 0;
    sm[t] = (unsigned char)mv;
  }
  const int allE = __syncthreads_and(mv);

  const unsigned short* wsb = wsw + (size_t)p * HYPE;
  const float* fc1b = p ? v_fc1b : w_fc1b;
  const float* outb = p ? v_outb : w_outb;
  const float* fc2b = p ? v_fc2b : w_fc2b;

  // ---- Phase A (co-op): x1 = relu(E @ W1 + b) -> sx1 [e][m] ----
  {
#pragma unroll
    for (int mi = 0; mi < 2; ++mi) {
      const int mt = wv * 2 + mi;
      bf16x8 af[3];
#pragma unroll
      for (int kt = 0; kt < 3; ++kt) {
        union { unsigned u32[4]; bf16x8 v8; } cv;
        cv.u32[0] = cvt_pk2(eu[mi][kt].x, eu[mi][kt].y);
        cv.u32[1] = cvt_pk2(eu[mi][kt].z, eu[mi][kt].w);
        cv.u32[2] = cvt_pk2(ev[mi][kt].x, ev[mi][kt].y);
        cv.u32[3] = cvt_pk2(ev[mi][kt].z, ev[mi][kt].w);
        af[kt] = cv.v8;
      }
#pragma unroll
      for (int nt = 0; nt < 8; ++nt) {
        f32x4 acc = {0.f, 0.f, 0.f, 0.f};
        const unsigned short* bp = wsb + OFF_W1 + (nt * 3) * 512 + ln * 8;
#pragma unroll
        for (int kt = 0; kt < 3; ++kt)
          acc = MFMA(af[kt], *(const bf16x8*)(bp + kt * 512), acc);
        const float bias = fc1b[nt * 16 + lr];
        f32x4 r;
        r[0] = fmaxf(acc[0] + bias, 0.f); r[1] = fmaxf(acc[1] + bias, 0.f);
        r[2] = fmaxf(acc[2] + bias, 0.f); r[3] = fmaxf(acc[3] + bias, 0.f);
        ctile_store(sx1, mt * 16 + lq * 4, nt * 16 + lr, r);
      }
    }
  }
  __syncthreads();  // B1: x1 complete

  // ---- Q (own head): Q_h[q][d] -> transpose via slice -> aQ ----
  {
    bf16x8 aq[4];
#pragma unroll
    for (int kt = 0; kt < 4; ++kt)
      aq[kt] = *(const bf16x8*)(sx1 + lr * ST + kt * 32 + lq * 8);
#pragma unroll
    for (int ni = 0; ni < 2; ++ni) {
      const int nt = wv * 2 + ni;
      f32x4 acc = {0.f, 0.f, 0.f, 0.f};
      const unsigned short* bp = wsb + OFF_WQ + (nt * 4) * 512 + ln * 8;
#pragma unroll
      for (int kt = 0; kt < 4; ++kt)
        acc = MFMA(aq[kt], *(const bf16x8*)(bp + kt * 512), acc);
      ctile_store(sS, lq * 4, ni * 16 + lr, acc);  // local d cols 0..31
    }
  }
  // hoist qW's global WK B-frags above the transpose drain (independent)
  bf16x8 wk[8];
#pragma unroll
  for (int nt = 0; nt < 8; ++nt)
    wk[nt] = *(const bf16x8*)(wsb + OFF_WK + (wv * 8 + nt) * 512 + ln * 8);
  LGKM0();
  const bf16x8 aQ = *(const bf16x8*)(sS + lr * ST + lq * 8);  // A[q][d0..31]

  // ---- qW = Q_h @ Wk_h^T (8 m-tiles) -> transpose -> aw ----
  {
    f32x4 Cw[8];
#pragma unroll
    for (int nt = 0; nt < 8; ++nt) {
      f32x4 acc = {0.f, 0.f, 0.f, 0.f};
      Cw[nt] = MFMA(aQ, wk[nt], acc);
    }
#pragma unroll
    for (int nt = 0; nt < 8; ++nt)
      ctile_store(sS, lq * 4, nt * 16 + lr, Cw[nt]);
  }
  LGKM0();
  bf16x8 aw[4];
#pragma unroll
  for (int kt = 0; kt < 4; ++kt)
    aw[kt] = *(const bf16x8*)(sS + lr * ST + kt * 32 + lq * 8);

  // ---- logits (full width, in-wave): Cl[nt] = qW @ x1^T ----
  f32x4 Cl[8];
  __builtin_amdgcn_s_setprio(1);
#pragma unroll
  for (int nt = 0; nt < 8; ++nt) {
    f32x4 acc = {0.f, 0.f, 0.f, 0.f};
#pragma unroll
    for (int kt = 0; kt < 4; ++kt) {
      const bf16x8 bx =
          *(const bf16x8*)(sx1 + (nt * 16 + lr) * ST + kt * 32 + lq * 8);
      acc = MFMA(aw[kt], bx, acc);
    }
    Cl[nt] = acc;
  }

  // ---- V^T mt=0 issued BEFORE softmax (independent): its MFMAs drain
  //      while softmax's serial VALU chain runs. ----
  f32x4 Cv0[8], Cv1[8];
  {
    bf16x8 av[4];
#pragma unroll
    for (int kt = 0; kt < 4; ++kt)
      av[kt] = *(const bf16x8*)(wsb + OFF_WV + ((wv * 2) * 4 + kt) * 512 +
                                ln * 8);
#pragma unroll
    for (int nt = 0; nt < 8; ++nt) {
      f32x4 acc = {0.f, 0.f, 0.f, 0.f};
#pragma unroll
      for (int kt = 0; kt < 4; ++kt) {
        const bf16x8 bx =
            *(const bf16x8*)(sx1 + (nt * 16 + lr) * ST + kt * 32 + lq * 8);
        acc = MFMA(av[kt], bx, acc);
      }
      Cv0[nt] = acc;
    }
  }
  __builtin_amdgcn_s_setprio(0);

  // ---- in-wave softmax over 128 cols; W stored to sS ----
  {
    float lv[8][4];
#pragma unroll
    for (int nt = 0; nt < 8; ++nt) {
      const int eM = sm[nt * 16 + lr];
#pragma unroll
      for (int r = 0; r < 4; ++r) lv[nt][r] = eM ? -1e9f : Cl[nt][r];
    }
    float mx[4], sl[4];
#pragma unroll
    for (int r = 0; r < 4; ++r) {
      float m = lv[0][r];
#pragma unroll
      for (int nt = 1; nt < 8; ++nt) m = fmaxf(m, lv[nt][r]);
      mx[r] = m;
    }
#pragma unroll
    for (int k = 1; k < 16; k <<= 1)
#pragma unroll
      for (int r = 0; r < 4; ++r) mx[r] = fmaxf(mx[r], __shfl_xor(mx[r], k));
    float ex[8][4];
#pragma unroll
    for (int r = 0; r < 4; ++r) sl[r] = 0.f;
#pragma unroll
    for (int nt = 0; nt < 8; ++nt)
#pragma unroll
      for (int r = 0; r < 4; ++r) {
        ex[nt][r] = __expf(lv[nt][r] - mx[r]);
        sl[r] += ex[nt][r];
      }
#pragma unroll
    for (int k = 1; k < 16; k <<= 1)
#pragma unroll
      for (int r = 0; r < 4; ++r) sl[r] += __shfl_xor(sl[r], k);
    float sc[4];
#pragma unroll
    for (int r = 0; r < 4; ++r)
      sc[r] = ((int)sm[lq * 4 + r] | allE) ? 0.f : (1.f / sl[r]);
#pragma unroll
    for (int nt = 0; nt < 8; ++nt) {
      f32x4 wv4;
#pragma unroll
      for (int r = 0; r < 4; ++r) wv4[r] = ex[nt][r] * sc[r];
      ctile_store(sS, lq * 4, nt * 16 + lr, wv4);  // W, overwrites qW
    }
  }

  // ---- V^T mt=1: hides the W-store -> aw2 round trip under 32 MFMAs ----
  __builtin_amdgcn_s_setprio(1);
  {
    bf16x8 av[4];
#pragma unroll
    for (int kt = 0; kt < 4; ++kt)
      av[kt] = *(const bf16x8*)(wsb + OFF_WV + ((wv * 2 + 1) * 4 + kt) * 512 +
                                ln * 8);
#pragma unroll
    for (int nt = 0; nt < 8; ++nt) {
      f32x4 acc = {0.f, 0.f, 0.f, 0.f};
#pragma unroll
      for (int kt = 0; kt < 4; ++kt) {
        const bf16x8 bx =
            *(const bf16x8*)(sx1 + (nt * 16 + lr) * ST + kt * 32 + lq * 8);
        acc = MFMA(av[kt], bx, acc);
      }
      Cv1[nt] = acc;
    }
  }
  __builtin_amdgcn_s_setprio(0);
  LGKM0();  // drains W-stores (and all prior LDS ops)
  bf16x8 aw2[4];
#pragma unroll
  for (int kt = 0; kt < 4; ++kt)
    aw2[kt] = *(const bf16x8*)(sS + lr * ST + kt * 32 + lq * 8);
  // sS (all slices) dead from here on.
  __syncthreads();  // B2: x1 dead -> vtbuf; slices dead -> sattn valid

  // ---- write V^T into own 32-row band of vtbuf; attn = W @ V_h ----
  {
#pragma unroll
    for (int nt = 0; nt < 8; ++nt)
      ctile_store(sx1, wv * 32 + lq * 4, nt * 16 + lr, Cv0[nt]);
#pragma unroll
    for (int nt = 0; nt < 8; ++nt)
      ctile_store(sx1, wv * 32 + 16 + lq * 4, nt * 16 + lr, Cv1[nt]);
  }
  LGKM0();
  {
#pragma unroll
    for (int ntd = 0; ntd < 2; ++ntd) {
      f32x4 acc = {0.f, 0.f, 0.f, 0.f};
#pragma unroll
      for (int kt = 0; kt < 4; ++kt) {
        const bf16x8 bv = *(const bf16x8*)(sx1 + (wv * 32 + ntd * 16 + lr) *
                                                     ST +
                                           kt * 32 + lq * 8);
        acc = MFMA(aw2[kt], bv, acc);
      }
      ctile_store(sattn, lq * 4, wv * 32 + ntd * 16 + lr, acc);
    }
  }
  // hoist OUT's WO B-frags across B3 (independent of sattn)
  bf16x8 wo[2][4];
#pragma unroll
  for (int ni = 0; ni < 2; ++ni) {
    const unsigned short* bp =
        wsb + OFF_WO + ((wv * 2 + ni) * 4) * 512 + ln * 8;
#pragma unroll
    for (int kt = 0; kt < 4; ++kt)
      wo[ni][kt] = *(const bf16x8*)(bp + kt * 512);
  }
  __syncthreads();  // B3: sattn complete; sout region (slice 1) writable

  // ---- OUT = attn @ Wo + bo -> sout (co-op, 2 n-tiles/wave) ----
  {
    bf16x8 aa[4];
#pragma unroll
    for (int kt = 0; kt < 4; ++kt)
      aa[kt] = *(const bf16x8*)(sattn + lr * ST + kt * 32 + lq * 8);
#pragma unroll
    for (int ni = 0; ni < 2; ++ni) {
      const int nt = wv * 2 + ni;
      f32x4 acc = {0.f, 0.f, 0.f, 0.f};
#pragma unroll
      for (int kt = 0; kt < 4; ++kt)
        acc = MFMA(aa[kt], wo[ni][kt], acc);
      const float bj = outb[nt * 16 + lr];
      f32x4 r;
      r[0] = acc[0] + bj; r[1] = acc[1] + bj;
      r[2] = acc[2] + bj; r[3] = acc[3] + bj;
      ctile_store(sout, lq * 4, nt * 16 + lr, r);
    }
  }
  // hoist X3's W2 B-frags across B4 (independent of sout)
  bf16x8 w2f[2][4];
#pragma unroll
  for (int nt = 0; nt < 2; ++nt) {
    const unsigned short* bp = wsb + OFF_W2 + (nt * 4) * 512 + ln * 8;
#pragma unroll
    for (int kt = 0; kt < 4; ++kt)
      w2f[nt][kt] = *(const bf16x8*)(bp + kt * 512);
  }
  __syncthreads();  // B4: sout complete

  // ---- X3 = out @ fc2 + b (redundant per wave), mask, row-sum ----
  {
    bf16x8 ao[4];
#pragma unroll
    for (int kt = 0; kt < 4; ++kt)
      ao[kt] = *(const bf16x8*)(sout + lr * ST + kt * 32 + lq * 8);
    f32x4 Cx[2];
#pragma unroll
    for (int nt = 0; nt < 2; ++nt) {
      f32x4 acc = {0.f, 0.f, 0.f, 0.f};
#pragma unroll
      for (int kt = 0; kt < 4; ++kt)
        acc = MFMA(ao[kt], w2f[nt][kt], acc);
      Cx[nt] = acc;
    }
    const float b0 = fc2b[lr], b1 = fc2b[16 + lr];
    float rs[4];
#pragma unroll
    for (int r = 0; r < 4; ++r) {
      const int row = lq * 4 + r;
      rs[r] = sm[row] ? 0.f : (Cx[0][r] + b0 + Cx[1][r] + b1);
    }
#pragma unroll
    for (int k = 1; k < 16; k <<= 1)
#pragma unroll
      for (int r = 0; r < 4; ++r) rs[r] += __shfl_xor(rs[r], k);
    if (wv == 0 && lr == 0) {
#pragma unroll
      for (int r = 0; r < 4; ++r) {
        const int q = lq * 4 + r;
        sres[q] = p ? rs[r] : fabsf(rs[r]) * (1.f / 32.f);
      }
    }
  }

  // sres is wave-0-private: wave-local drain suffices (no block barrier)
  LGKM0();
  if (t == 0) {
    float s = 0.f;
    if (p == 0) {
      const float* qs = agent_qs + (size_t)b * NA;
#pragma unroll
      for (int q = 0; q < NA; ++q) s += qs[q] * sres[q];
    } else {
#pragma unroll
      for (int q = 0; q < NA; ++q) s += sres[q];
      s *= (1.f / 512.f);
    }
    atomicAdd(out_g + b, s);  // out zeroed by harness memset; 2 addends/b
  }
}

extern "C" void kernel_launch(void* const* d_in, const int* in_sizes, int n_in,
                              void* d_out, int out_size, void* d_ws,
                              size_t ws_size, hipStream_t stream) {
  (void)n_in; (void)out_size; (void)ws_size;
  const int nb = in_sizes[0] / NA;  // BS*T = 1600
  unsigned short* wsw = (unsigned short*)d_ws;
  int* mflag = (int*)((char*)d_ws + WS_FLAG_OFF);

  hipLaunchKernelGGL(prep_kernel, dim3(81), dim3(256), 0, stream,
                     (const float*)d_in[3], (const float*)d_in[5],
                     (const float*)d_in[6], (const float*)d_in[8],
                     (const float*)d_in[10], (const float*)d_in[12],
                     (const float*)d_in[13], (const float*)d_in[15],
                     (const unsigned char*)d_in[2], wsw, mflag);
  hipLaunchKernelGGL(qmix_mfma, dim3(nb * 2), dim3(256), 0, stream,
                     (const float*)d_in[0], (const float*)d_in[1],
                     (const unsigned char*)d_in[2], (const unsigned short*)wsw,
                     (const int*)mflag, (const float*)d_in[4],
                     (const float*)d_in[7], (const float*)d_in[9],
                     (const float*)d_in[11], (const float*)d_in[14],
                     (const float*)d_in[16], (float*)d_out);
}

// Round 9
// 241.888 us; speedup vs baseline: 1.0460x; 1.0076x over previous
//
#include <hip/hip_runtime.h>
#include <hip/hip_bf16.h>

// LinearFlexQMixer MI355X — round 17: algebraic collapse of OUT+X3.
// rowmean(x3) = attn·h + c0 with h = out_w @ mean(fc2_w,axis=1),
// c0 = out_b·gm + mean(fc2_b): the entire OUT (attn@Wo+bo) and X3 (out@fc2)
// phases + B3 + B4 + 4 LDS round trips collapse into a 2-FMA/thread dot of
// the f32 attn accumulators with precomputed h, one 16-lane shfl reduce,
// one cross-wave LDS combine. Row-masking commutes (row-wise dependency).
// Precision improves (attn stays f32; fewer bf16 roundings) — absmax will
// shift, must stay <= 1.11e-2. prep: drop WO/W2 frag tiles (120 tiles/p),
// add per-p h/c0 block (stored at the freed OFF_WO region). Grid 81->63.
// Front half (through attn MFMAs) byte-identical to R16.

#define NA 16
#define NEn 128
#define EDm 96
#define ST 136  // LDS row stride (shorts); 272B rows -> <=2-way conflicts

typedef __attribute__((ext_vector_type(8))) short bf16x8;
typedef __attribute__((ext_vector_type(4))) float f32x4;

#define MFMA(a, b, c) __builtin_amdgcn_mfma_f32_16x16x32_bf16((a), (b), (c), 0, 0, 0)
#define LGKM0() __asm__ volatile("s_waitcnt lgkmcnt(0)" ::: "memory")

// d_ws layout (bf16 elems), per hypernet p at p*HYPE:
#define OFF_W1 0       // [nt8][kt3][64][8]  B-frags Phase A (fc1w)
#define OFF_WQ 12288   // [nt8][kt4][64][8]  B-frags Q (inw cols 0:128, pre-scaled)
#define OFF_WK 28672   // [h4][nt8][64][8]   B-frags qW (Wk^T per head, K=32)
#define OFF_WV 45056   // [h4][mt2][kt4][64][8] A-frags V^T (Wv^T per head)
#define OFF_WO 61440   // REUSED: f32 h[128] + c0 (h = Wo@gm, c0 = bo·gm+bm)
#define HYPE 81920
#define WS_FLAG_OFF 327680  // int flag: mask dtype (1 => int32)

__device__ __forceinline__ unsigned short f2bf(float f) {
  unsigned u = __float_as_uint(f);
  u += 0x7fffu + ((u >> 16) & 1u);  // RNE
  return (unsigned short)(u >> 16);
}

// Pack two f32 -> dword of 2 bf16 (RNE) via HW v_cvt_pk_bf16_f32.
__device__ __forceinline__ unsigned cvt_pk2(float lo, float hi) {
  union { __hip_bfloat162 h2; unsigned u; } cv;
  cv.h2 = __float22bfloat162_rn(float2{lo, hi});
  return cv.u;
}

// Store one 16x16 C-tile column (4 f32, rows row0+0..3, col) as bf16 into
// LDS row-major [..][ST]. Pairs lanes (col, col^1) via shfl so every dword
// is written by exactly one lane. Full-wave calls only.
__device__ __forceinline__ void ctile_store(unsigned short* dst, int row0,
                                            int col, f32x4 v) {
  unsigned x = cvt_pk2(v[0], v[1]);
  unsigned y = cvt_pk2(v[2], v[3]);
  unsigned ox = (unsigned)__shfl_xor((int)x, 1);
  unsigned oy = (unsigned)__shfl_xor((int)y, 1);
  unsigned w0, w1;
  int ra;
  if ((threadIdx.x & 1) == 0) {
    ra = 0;
    w0 = (x & 0xffffu) | (ox << 16);
    w1 = (x >> 16) | (ox & 0xffff0000u);
  } else {
    ra = 2;
    w0 = (oy & 0xffffu) | (y << 16);
    w1 = (oy >> 16) | (y & 0xffff0000u);
  }
  *(unsigned*)(dst + (row0 + ra) * ST + (col & ~1)) = w0;
  *(unsigned*)(dst + (row0 + ra + 1) * ST + (col & ~1)) = w1;
}

// ---- prep: 60 work blocks (120 tiles/p: W1 24 | WQ 32 | WK 32 | WV 32)
//      + block 60: mask-dtype sniff + blocks 61/62: per-p h/c0.
__global__ void prep_kernel(const float* __restrict__ w_fc1w,
                            const float* __restrict__ w_inw,
                            const float* __restrict__ w_outw,
                            const float* __restrict__ w_fc2w,
                            const float* __restrict__ v_fc1w,
                            const float* __restrict__ v_inw,
                            const float* __restrict__ v_outw,
                            const float* __restrict__ v_fc2w,
                            const float* __restrict__ w_outb,
                            const float* __restrict__ w_fc2b,
                            const float* __restrict__ v_outb,
                            const float* __restrict__ v_fc2b,
                            const unsigned char* __restrict__ mask,
                            unsigned short* __restrict__ ws,
                            int* __restrict__ flag) {
  if (blockIdx.x == 60) {
    const uint4 v = *(const uint4*)(mask + threadIdx.x * 16);
    const unsigned nz = (v.x | v.y | v.z | v.w) & 0xffffff00u;
    const int any = __syncthreads_or((int)(nz != 0));
    if (threadIdx.x == 0) *flag = (any == 0) ? 1 : 0;
    return;
  }
  if (blockIdx.x >= 61) {
    // h/c0 block: gm = mean(fc2w, axis=1); h = outw @ gm; c0 = bo·gm + bm.
    const int hp = blockIdx.x - 61;
    const float* fc2w = hp ? v_fc2w : w_fc2w;
    const float* outw = hp ? v_outw : w_outw;
    const float* outb = hp ? v_outb : w_outb;
    const float* fc2b = hp ? v_fc2b : w_fc2b;
    float* hdst = (float*)(ws + (size_t)hp * HYPE + OFF_WO);
    __shared__ float sgm[128];
    const int t = threadIdx.x;
    if (t < 128) {
      float g = 0.f;
#pragma unroll
      for (int c = 0; c < 32; ++c) g += fc2w[t * 32 + c];
      sgm[t] = g * (1.f / 32.f);
    }
    __syncthreads();
    if (t < 128) {
      float hh = 0.f;
      for (int m = 0; m < 128; ++m) hh += outw[t * 128 + m] * sgm[m];
      hdst[t] = hh;
    }
    if (t == 0) {
      float c0 = 0.f;
      for (int m = 0; m < 128; ++m) c0 += outb[m] * sgm[m];
      float bm = 0.f;
#pragma unroll
      for (int c = 0; c < 32; ++c) bm += fc2b[c];
      hdst[128] = c0 + bm * (1.f / 32.f);
    }
    return;
  }
  const int g = blockIdx.x * 256 + threadIdx.x;  // 0 .. 15359
  const int p = (g >= 7680) ? 1 : 0;
  const int i = g - p * 7680;
  const int l = i & 63;
  const int tt = i >> 6;  // 0..119
  const int lhi = l >> 4, lo = l & 15;
  const float* fc1w = p ? v_fc1w : w_fc1w;
  const float* inw = p ? v_inw : w_inw;
  unsigned short* wsp = ws + p * HYPE;

  float v8[8];
  unsigned short* dst;
  if (tt < 24) {
    const int nt = tt / 3, kt = tt - nt * 3;
    const float* src = fc1w + (kt * 32 + lhi * 8) * 128 + nt * 16 + lo;
#pragma unroll
    for (int j = 0; j < 8; ++j) v8[j] = src[j * 128];
    dst = wsp + OFF_W1 + tt * 512 + l * 8;
  } else if (tt < 56) {
    const int t2 = tt - 24;
    const int nt = t2 >> 2, kt = t2 & 3;
    const float* src = inw + (kt * 32 + lhi * 8) * 384 + nt * 16 + lo;
#pragma unroll
    for (int j = 0; j < 8; ++j) v8[j] = src[j * 384] * 0.17677669529663687f;
    dst = wsp + OFF_WQ + t2 * 512 + l * 8;
  } else if (tt < 88) {
    const int t2 = tt - 56;
    const int h = t2 >> 3, nt = t2 & 7;
    const float* src = inw + (nt * 16 + lo) * 384 + 128 + h * 32 + lhi * 8;
#pragma unroll
    for (int j = 0; j < 8; ++j) v8[j] = src[j];
    dst = wsp + OFF_WK + t2 * 512 + l * 8;
  } else {
    const int t2 = tt - 88;
    const int kt = t2 & 3, q = t2 >> 2;
    const int h = q >> 1, mt = q & 1;
    const float* src =
        inw + (kt * 32 + lhi * 8) * 384 + 256 + h * 32 + mt * 16 + lo;
#pragma unroll
    for (int j = 0; j < 8; ++j) v8[j] = src[j * 384];
    dst = wsp + OFF_WV + t2 * 512 + l * 8;
  }
  bf16x8 o;
#pragma unroll
  for (int j = 0; j < 8; ++j) o[j] = (short)f2bf(v8[j]);
  *(bf16x8*)dst = o;
}

// LDS (bytes) — R17 map:
//   sx1 / vtbuf [128][136]bf16   0..34816
//   sSlice 4x[16][136]           34816..52224  (per-wave transpose slices)
//     sP f32[4][16] ALIASES sSlice+0  (live post-attn only; slices dead)
//   sm   u8[128]                 52224..52352
// 52,352 B/block -> 3 blocks/CU resource limit (160KB/CU).
#define SMEM_BYTES 52352

__global__ __launch_bounds__(256, 2) void qmix_mfma(
    const float* __restrict__ agent_qs, const float* __restrict__ entities,
    const unsigned char* __restrict__ emask_g,
    const unsigned short* __restrict__ wsw, const int* __restrict__ mflag,
    const float* __restrict__ w_fc1b, const float* __restrict__ v_fc1b,
    float* __restrict__ out_g) {
  const int t = threadIdx.x;
  const int wv = t >> 6;  // wave == head
  const int ln = t & 63;
  const int lr = ln & 15;
  const int lq = ln >> 4;
  const int b = blockIdx.x >> 1;   // batch element
  const int p = blockIdx.x & 1;    // hypernet (0: w1, 1: v)
  const float* ents = entities + (size_t)b * (NEn * EDm);

  __shared__ __align__(16) unsigned char smem[SMEM_BYTES];
  unsigned short* sx1 = (unsigned short*)smem;  // also vtbuf
  unsigned short* sSlice = sx1 + 17408;         // 4 slices
  float* sP = (float*)sSlice;                   // alias: live post-attn only
  unsigned char* sm = smem + 52224;
  unsigned short* sS = sSlice + wv * 16 * ST;  // this wave's slice

  // ---- E-prefetch: issue Phase A's HBM loads before anything else ----
  float4 eu[2][3], ev[2][3];
#pragma unroll
  for (int mi = 0; mi < 2; ++mi) {
    const float* erow = ents + ((wv * 2 + mi) * 16 + lr) * EDm + lq * 8;
#pragma unroll
    for (int kt = 0; kt < 3; ++kt) {
      eu[mi][kt] = *(const float4*)(erow + kt * 32);
      ev[mi][kt] = *(const float4*)(erow + kt * 32 + 4);
    }
  }

  // ---- entity mask (dtype-normalized) ----
  const int is_i32 = *mflag;
  int mv = 1;
  if (t < NEn) {
    if (is_i32)
      mv = (((const int*)emask_g)[(size_t)b * NEn + t] != 0) ? 1 : 0;
    else
      mv = (emask_g[(size_t)b * NEn + t] != 0) ? 1 : 0;
    sm[t] = (unsigned char)mv;
  }
  const int allE = __syncthreads_and(mv);

  const unsigned short* wsb = wsw + (size_t)p * HYPE;
  const float* fc1b = p ? v_fc1b : w_fc1b;
  const float* hws = (const float*)(wsb + OFF_WO);  // h[128], c0 at [128]

  // ---- Phase A (co-op): x1 = relu(E @ W1 + b) -> sx1 [e][m] ----
  {
#pragma unroll
    for (int mi = 0; mi < 2; ++mi) {
      const int mt = wv * 2 + mi;
      bf16x8 af[3];
#pragma unroll
      for (int kt = 0; kt < 3; ++kt) {
        union { unsigned u32[4]; bf16x8 v8; } cv;
        cv.u32[0] = cvt_pk2(eu[mi][kt].x, eu[mi][kt].y);
        cv.u32[1] = cvt_pk2(eu[mi][kt].z, eu[mi][kt].w);
        cv.u32[2] = cvt_pk2(ev[mi][kt].x, ev[mi][kt].y);
        cv.u32[3] = cvt_pk2(ev[mi][kt].z, ev[mi][kt].w);
        af[kt] = cv.v8;
      }
#pragma unroll
      for (int nt = 0; nt < 8; ++nt) {
        f32x4 acc = {0.f, 0.f, 0.f, 0.f};
        const unsigned short* bp = wsb + OFF_W1 + (nt * 3) * 512 + ln * 8;
#pragma unroll
        for (int kt = 0; kt < 3; ++kt)
          acc = MFMA(af[kt], *(const bf16x8*)(bp + kt * 512), acc);
        const float bias = fc1b[nt * 16 + lr];
        f32x4 r;
        r[0] = fmaxf(acc[0] + bias, 0.f); r[1] = fmaxf(acc[1] + bias, 0.f);
        r[2] = fmaxf(acc[2] + bias, 0.f); r[3] = fmaxf(acc[3] + bias, 0.f);
        ctile_store(sx1, mt * 16 + lq * 4, nt * 16 + lr, r);
      }
    }
  }
  __syncthreads();  // B1: x1 complete

  // ---- Q (own head): Q_h[q][d] -> transpose via slice -> aQ ----
  {
    bf16x8 aq[4];
#pragma unroll
    for (int kt = 0; kt < 4; ++kt)
      aq[kt] = *(const bf16x8*)(sx1 + lr * ST + kt * 32 + lq * 8);
#pragma unroll
    for (int ni = 0; ni < 2; ++ni) {
      const int nt = wv * 2 + ni;
      f32x4 acc = {0.f, 0.f, 0.f, 0.f};
      const unsigned short* bp = wsb + OFF_WQ + (nt * 4) * 512 + ln * 8;
#pragma unroll
      for (int kt = 0; kt < 4; ++kt)
        acc = MFMA(aq[kt], *(const bf16x8*)(bp + kt * 512), acc);
      ctile_store(sS, lq * 4, ni * 16 + lr, acc);  // local d cols 0..31
    }
  }
  // hoist qW's global WK B-frags above the transpose drain (independent)
  bf16x8 wk[8];
#pragma unroll
  for (int nt = 0; nt < 8; ++nt)
    wk[nt] = *(const bf16x8*)(wsb + OFF_WK + (wv * 8 + nt) * 512 + ln * 8);
  // hoist h slice loads (constants, L2-hot)
  const float h0 = hws[wv * 32 + lr];
  const float h1 = hws[wv * 32 + 16 + lr];
  LGKM0();
  const bf16x8 aQ = *(const bf16x8*)(sS + lr * ST + lq * 8);  // A[q][d0..31]

  // ---- qW = Q_h @ Wk_h^T (8 m-tiles) -> transpose -> aw ----
  {
    f32x4 Cw[8];
#pragma unroll
    for (int nt = 0; nt < 8; ++nt) {
      f32x4 acc = {0.f, 0.f, 0.f, 0.f};
      Cw[nt] = MFMA(aQ, wk[nt], acc);
    }
#pragma unroll
    for (int nt = 0; nt < 8; ++nt)
      ctile_store(sS, lq * 4, nt * 16 + lr, Cw[nt]);
  }
  LGKM0();
  bf16x8 aw[4];
#pragma unroll
  for (int kt = 0; kt < 4; ++kt)
    aw[kt] = *(const bf16x8*)(sS + lr * ST + kt * 32 + lq * 8);

  // ---- logits (full width, in-wave): Cl[nt] = qW @ x1^T ----
  f32x4 Cl[8];
  __builtin_amdgcn_s_setprio(1);
#pragma unroll
  for (int nt = 0; nt < 8; ++nt) {
    f32x4 acc = {0.f, 0.f, 0.f, 0.f};
#pragma unroll
    for (int kt = 0; kt < 4; ++kt) {
      const bf16x8 bx =
          *(const bf16x8*)(sx1 + (nt * 16 + lr) * ST + kt * 32 + lq * 8);
      acc = MFMA(aw[kt], bx, acc);
    }
    Cl[nt] = acc;
  }

  // ---- V^T mt=0 issued BEFORE softmax (independent): its MFMAs drain
  //      while softmax's serial VALU chain runs. ----
  f32x4 Cv0[8], Cv1[8];
  {
    bf16x8 av[4];
#pragma unroll
    for (int kt = 0; kt < 4; ++kt)
      av[kt] = *(const bf16x8*)(wsb + OFF_WV + ((wv * 2) * 4 + kt) * 512 +
                                ln * 8);
#pragma unroll
    for (int nt = 0; nt < 8; ++nt) {
      f32x4 acc = {0.f, 0.f, 0.f, 0.f};
#pragma unroll
      for (int kt = 0; kt < 4; ++kt) {
        const bf16x8 bx =
            *(const bf16x8*)(sx1 + (nt * 16 + lr) * ST + kt * 32 + lq * 8);
        acc = MFMA(av[kt], bx, acc);
      }
      Cv0[nt] = acc;
    }
  }
  __builtin_amdgcn_s_setprio(0);

  // ---- in-wave softmax over 128 cols; W stored to sS ----
  {
    float lv[8][4];
#pragma unroll
    for (int nt = 0; nt < 8; ++nt) {
      const int eM = sm[nt * 16 + lr];
#pragma unroll
      for (int r = 0; r < 4; ++r) lv[nt][r] = eM ? -1e9f : Cl[nt][r];
    }
    float mx[4], sl[4];
#pragma unroll
    for (int r = 0; r < 4; ++r) {
      float m = lv[0][r];
#pragma unroll
      for (int nt = 1; nt < 8; ++nt) m = fmaxf(m, lv[nt][r]);
      mx[r] = m;
    }
#pragma unroll
    for (int k = 1; k < 16; k <<= 1)
#pragma unroll
      for (int r = 0; r < 4; ++r) mx[r] = fmaxf(mx[r], __shfl_xor(mx[r], k));
    float ex[8][4];
#pragma unroll
    for (int r = 0; r < 4; ++r) sl[r] = 0.f;
#pragma unroll
    for (int nt = 0; nt < 8; ++nt)
#pragma unroll
      for (int r = 0; r < 4; ++r) {
        ex[nt][r] = __expf(lv[nt][r] - mx[r]);
        sl[r] += ex[nt][r];
      }
#pragma unroll
    for (int k = 1; k < 16; k <<= 1)
#pragma unroll
      for (int r = 0; r < 4; ++r) sl[r] += __shfl_xor(sl[r], k);
    float sc[4];
#pragma unroll
    for (int r = 0; r < 4; ++r)
      sc[r] = ((int)sm[lq * 4 + r] | allE) ? 0.f : (1.f / sl[r]);
#pragma unroll
    for (int nt = 0; nt < 8; ++nt) {
      f32x4 wv4;
#pragma unroll
      for (int r = 0; r < 4; ++r) wv4[r] = ex[nt][r] * sc[r];
      ctile_store(sS, lq * 4, nt * 16 + lr, wv4);  // W, overwrites qW
    }
  }

  // ---- V^T mt=1: hides the W-store -> aw2 round trip under 32 MFMAs ----
  __builtin_amdgcn_s_setprio(1);
  {
    bf16x8 av[4];
#pragma unroll
    for (int kt = 0; kt < 4; ++kt)
      av[kt] = *(const bf16x8*)(wsb + OFF_WV + ((wv * 2 + 1) * 4 + kt) * 512 +
                                ln * 8);
#pragma unroll
    for (int nt = 0; nt < 8; ++nt) {
      f32x4 acc = {0.f, 0.f, 0.f, 0.f};
#pragma unroll
      for (int kt = 0; kt < 4; ++kt) {
        const bf16x8 bx =
            *(const bf16x8*)(sx1 + (nt * 16 + lr) * ST + kt * 32 + lq * 8);
        acc = MFMA(av[kt], bx, acc);
      }
      Cv1[nt] = acc;
    }
  }
  __builtin_amdgcn_s_setprio(0);
  LGKM0();  // drains W-stores (and all prior LDS ops)
  bf16x8 aw2[4];
#pragma unroll
  for (int kt = 0; kt < 4; ++kt)
    aw2[kt] = *(const bf16x8*)(sS + lr * ST + kt * 32 + lq * 8);
  // sS (all slices) dead from here on.
  __syncthreads();  // B2: x1 dead -> vtbuf; slices dead

  // ---- write V^T into own 32-row band of vtbuf; attn = W @ V_h (f32) ----
  {
#pragma unroll
    for (int nt = 0; nt < 8; ++nt)
      ctile_store(sx1, wv * 32 + lq * 4, nt * 16 + lr, Cv0[nt]);
#pragma unroll
    for (int nt = 0; nt < 8; ++nt)
      ctile_store(sx1, wv * 32 + 16 + lq * 4, nt * 16 + lr, Cv1[nt]);
  }
  LGKM0();
  f32x4 Ca[2];
#pragma unroll
  for (int ntd = 0; ntd < 2; ++ntd) {
    f32x4 acc = {0.f, 0.f, 0.f, 0.f};
#pragma unroll
    for (int kt = 0; kt < 4; ++kt) {
      const bf16x8 bv = *(const bf16x8*)(sx1 + (wv * 32 + ntd * 16 + lr) * ST +
                                         kt * 32 + lq * 8);
      acc = MFMA(aw2[kt], bv, acc);
    }
    Ca[ntd] = acc;
  }

  // ---- rowmean = attn·h + c0 (OUT+X3 collapsed): dot, reduce, combine ----
  {
    float part[4];
#pragma unroll
    for (int r = 0; r < 4; ++r) part[r] = Ca[0][r] * h0 + Ca[1][r] * h1;
#pragma unroll
    for (int k = 1; k < 16; k <<= 1)
#pragma unroll
      for (int r = 0; r < 4; ++r) part[r] += __shfl_xor(part[r], k);
    if (lr == 0) {
#pragma unroll
      for (int r = 0; r < 4; ++r) sP[wv * 16 + lq * 4 + r] = part[r];
    }
  }
  __syncthreads();  // sP complete (all 4 waves)

  if (t == 0) {
    const float c0 = hws[128];
    float s = 0.f;
    if (p == 0) {
      const float* qs = agent_qs + (size_t)b * NA;
#pragma unroll
      for (int row = 0; row < NA; ++row) {
        float tot = sP[row] + sP[16 + row] + sP[32 + row] + sP[48 + row] + c0;
        tot = sm[row] ? 0.f : tot;
        s += qs[row] * fabsf(tot);
      }
    } else {
#pragma unroll
      for (int row = 0; row < NA; ++row) {
        float tot = sP[row] + sP[16 + row] + sP[32 + row] + sP[48 + row] + c0;
        s += sm[row] ? 0.f : tot;
      }
      s *= (1.f / 16.f);
    }
    atomicAdd(out_g + b, s);  // out zeroed by harness memset; 2 addends/b
  }
}

extern "C" void kernel_launch(void* const* d_in, const int* in_sizes, int n_in,
                              void* d_out, int out_size, void* d_ws,
                              size_t ws_size, hipStream_t stream) {
  (void)n_in; (void)out_size; (void)ws_size;
  const int nb = in_sizes[0] / NA;  // BS*T = 1600
  unsigned short* wsw = (unsigned short*)d_ws;
  int* mflag = (int*)((char*)d_ws + WS_FLAG_OFF);

  hipLaunchKernelGGL(prep_kernel, dim3(63), dim3(256), 0, stream,
                     (const float*)d_in[3], (const float*)d_in[5],
                     (const float*)d_in[6], (const float*)d_in[8],
                     (const float*)d_in[10], (const float*)d_in[12],
                     (const float*)d_in[13], (const float*)d_in[15],
                     (const float*)d_in[7], (const float*)d_in[9],
                     (const float*)d_in[14], (const float*)d_in[16],
                     (const unsigned char*)d_in[2], wsw, mflag);
  hipLaunchKernelGGL(qmix_mfma, dim3(nb * 2), dim3(256), 0, stream,
                     (const float*)d_in[0], (const float*)d_in[1],
                     (const unsigned char*)d_in[2], (const unsigned short*)wsw,
                     (const int*)mflag, (const float*)d_in[4],
                     (const float*)d_in[11], (float*)d_out);
}